// Round 3
// baseline (189.839 us; speedup 1.0000x reference)
//
#include <hip/hip_runtime.h>
#include <hip/hip_bf16.h>
#include <math.h>

#define BATCH 4
#define N 2048
#define D 256
#define NH 4
#define DH 64
#define TOPK 9
#define NEG_BIG -1e30f

typedef __bf16 bf16;
typedef __bf16 bf16x4 __attribute__((ext_vector_type(4)));
typedef __bf16 bf16x8 __attribute__((ext_vector_type(8)));
typedef float f32x4 __attribute__((ext_vector_type(4)));

#define PK3(a,b,c) ((a) | ((b) << 2) | ((c) << 4))
#define PK6(a,b,c,d,e,f) ((a) | ((b) << 2) | ((c) << 4) | ((d) << 6) | ((e) << 8) | ((f) << 10))

// s_waitcnt with ONLY vmcnt=N. gfx9 encoding: vmcnt[3:0]@0, expcnt@4,
// lgkmcnt@8, vmcnt[5:4]@14.
#define WAITVM(Nc) __builtin_amdgcn_s_waitcnt((((Nc) & 0xf)) | (7u << 4) | (0xfu << 8) | ((((unsigned)(Nc)) >> 4) << 14))

__device__ __forceinline__ void async_cp16(const bf16* g, const bf16* l) {
  __builtin_amdgcn_global_load_lds(
      (const __attribute__((address_space(1))) void*)(uintptr_t)g,
      (__attribute__((address_space(3))) void*)(uintptr_t)l, 16, 0, 0);
}

// ---------------------------------------------------------------------------
// prep: blk<8192: x -> XsN (L2-norm, 2-way split h/m, stride 512) + norms
//       blk<9216: W{q,k,v,o} -> Wt (transpose + 2-way split)
//       else (128 blks): zero the 2 MB adjacency mask
// ---------------------------------------------------------------------------
__global__ __launch_bounds__(64) void prep_kernel(const float* __restrict__ x,
                                                  const float* __restrict__ Wq,
                                                  const float* __restrict__ Wk,
                                                  const float* __restrict__ Wv,
                                                  const float* __restrict__ Wo,
                                                  bf16* __restrict__ XsN,
                                                  bf16* __restrict__ Wt,
                                                  float* __restrict__ norms,
                                                  uint4* __restrict__ mask4) {
  int blk = blockIdx.x;
  int lane = threadIdx.x;
  if (blk < 8192) {
    float4 v = *(const float4*)(x + (size_t)blk * D + lane * 4);
    float ss = v.x * v.x + v.y * v.y + v.z * v.z + v.w * v.w;
    for (int off = 32; off; off >>= 1) ss += __shfl_down(ss, off);
    ss = __shfl(ss, 0);
    float nrm = fmaxf(sqrtf(ss), 1e-12f);
    if (lane == 0) norms[blk] = nrm;
    float sc = 1.0f / nrm;
    float xs[4] = {v.x * sc, v.y * sc, v.z * sc, v.w * sc};
    bf16* o = XsN + (size_t)blk * 512 + lane * 4;
#pragma unroll
    for (int j = 0; j < 4; ++j) {
      float xv = xs[j];
      bf16 h = (bf16)xv;
      o[j] = h;
      o[256 + j] = (bf16)(xv - (float)h);
    }
  } else if (blk < 9216) {
    int jj = blk - 8192;
    const float* W = (jj < 256) ? Wq : (jj < 512) ? Wk : (jj < 768) ? Wv : Wo;
    int j = jj & 255;
    bf16* dst = Wt + (size_t)jj * 512;
    for (int k = lane; k < 256; k += 64) {
      float w = W[(size_t)k * D + j];
      bf16 h = (bf16)w;
      dst[k] = h;
      dst[256 + k] = (bf16)(w - (float)h);
    }
  } else {
    int base = (blk - 9216) * 1024 + lane;
#pragma unroll
    for (int t = 0; t < 16; ++t)
      mask4[base + t * 64] = make_uint4(0, 0, 0, 0);
  }
}

// ---------------------------------------------------------------------------
// 256x256 8-wave GEMM core (round 2).  BK=64, LDS 2x64KB dbuf, 4 phases per
// K-tile: {ds-read subtile || stage half-tile} -> barrier -> setprio(1) +
// 16 MFMA + setprio(0) -> barrier.  Staging issued at ph0/ph1, drained once
// per K-tile (WAITVM(0) at ph3 end, ~2.5 phases of slack).  Swizzle: 16B
// slot ^ (row&7) on 128B rows — proven 0-conflict in this kernel's BK=64
// ancestor.  K-slice order identical to the 128^2 core -> sim bit-identical.
// outmode 1: fp32 nontemporal + optional mirror (sim).
// outmode 2: bf16 with per-row norm rescale (qkv).
// ---------------------------------------------------------------------------
__device__ __forceinline__ void gemm_core256(bf16* S,
                                             const bf16* __restrict__ Ab,
                                             const bf16* __restrict__ Bb,
                                             void* __restrict__ Cvoid,
                                             int ldc, int ntiles,
                                             int amap, int bmap,
                                             int row0, int col0,
                                             int outmode, bool mirror,
                                             const float* __restrict__ rowscale) {
  int tid = threadIdx.x;
  int lane = tid & 63;
  int wv = tid >> 6;                 // 8 waves: 2M x 4N
  int wm = (wv >> 2) * 128;          // wave's A half (rows)
  int wn = (wv & 3) * 64;            // wave's 64 cols
  int aht = wv >> 2;                 // LDS half-tile for A: 0/1
  int bht = 2 + ((wv & 3) >> 1);     // LDS half-tile for B: 2/3
  int brow = (wv & 1) * 64;          // row base within B half

  int fr = lane & 15;
  int fq = lane >> 4;                // k slot quarter 0..3

  // staging: 2 16B-slots per thread per half-tile (1024 slots = 128 rows x 8)
  int s0 = tid, s1 = tid + 512;
  int r0 = s0 >> 3, sl0 = s0 & 7;
  int r1 = s1 >> 3, sl1 = s1 & 7;
  int gc0 = (sl0 ^ (r0 & 7)) << 3;   // pre-swizzled global column (elems)
  int gc1 = (sl1 ^ (r1 & 7)) << 3;

  f32x4 acc[8][4] = {};

  auto koffs = [&](int kt, int map) {
    return (((map >> ((kt >> 2) * 2)) & 3) << 8) | ((kt & 3) << 6);
  };
  // half01 0: A halves (ht0+ht1); 1: B halves (ht2+ht3).  4 loads.
  auto stageAB = [&](int kt, int buf, int half01) {
    const bf16* Base = half01 ? Bb : Ab;
    int koff = koffs(kt, half01 ? bmap : amap);
    bf16* d = S + buf * 32768 + half01 * 16384;
    const bf16* b0 = Base + koff;
    async_cp16(b0 + (size_t)r0 * 512 + gc0, d + s0 * 8);
    async_cp16(b0 + (size_t)r1 * 512 + gc1, d + s1 * 8);
    async_cp16(b0 + (size_t)(128 + r0) * 512 + gc0, d + 8192 + s0 * 8);
    async_cp16(b0 + (size_t)(128 + r1) * 512 + gc1, d + 8192 + s1 * 8);
  };
  auto readA = [&](bf16x8* af, int buf, int hm, int ks) {
#pragma unroll
    for (int i = 0; i < 4; ++i) {
      int r = hm * 64 + i * 16 + fr;
      int c = ks * 4 + fq;
      af[i] = *(const bf16x8*)&S[buf * 32768 + aht * 8192 + r * 64 + ((c ^ (r & 7)) << 3)];
    }
  };
  auto readB = [&](bf16x8* bb, int buf, int ks) {
#pragma unroll
    for (int nj = 0; nj < 4; ++nj) {
      int r = brow + nj * 16 + fr;
      int c = ks * 4 + fq;
      bb[nj] = *(const bf16x8*)&S[buf * 32768 + bht * 8192 + r * 64 + ((c ^ (r & 7)) << 3)];
    }
  };

  // prologue: stage K-tile 0 into buf0, drain, publish.
  stageAB(0, 0, 0);
  stageAB(0, 0, 1);
  WAITVM(0);
  __builtin_amdgcn_s_barrier();

  for (int kt = 0; kt < ntiles; ++kt) {
    int buf = kt & 1;
    bool more = (kt + 1 < ntiles);
    bf16x8 af[4], bb[4];
    // ---- ph0: B(ks0) + A(hm0,ks0); stage next A halves
    readB(bb, buf, 0);
    readA(af, buf, 0, 0);
    if (more) stageAB(kt + 1, buf ^ 1, 0);
    __builtin_amdgcn_s_barrier();
    __builtin_amdgcn_s_setprio(1);
#pragma unroll
    for (int i = 0; i < 4; ++i)
#pragma unroll
      for (int nj = 0; nj < 4; ++nj)
        acc[i][nj] = __builtin_amdgcn_mfma_f32_16x16x32_bf16(af[i], bb[nj], acc[i][nj], 0, 0, 0);
    __builtin_amdgcn_s_setprio(0);
    __builtin_amdgcn_s_barrier();
    // ---- ph1: A(hm1,ks0); stage next B halves
    readA(af, buf, 1, 0);
    if (more) stageAB(kt + 1, buf ^ 1, 1);
    __builtin_amdgcn_s_barrier();
    __builtin_amdgcn_s_setprio(1);
#pragma unroll
    for (int i = 0; i < 4; ++i)
#pragma unroll
      for (int nj = 0; nj < 4; ++nj)
        acc[4 + i][nj] = __builtin_amdgcn_mfma_f32_16x16x32_bf16(af[i], bb[nj], acc[4 + i][nj], 0, 0, 0);
    __builtin_amdgcn_s_setprio(0);
    __builtin_amdgcn_s_barrier();
    // ---- ph2: B(ks1) + A(hm0,ks1)
    readB(bb, buf, 1);
    readA(af, buf, 0, 1);
    __builtin_amdgcn_s_barrier();
    __builtin_amdgcn_s_setprio(1);
#pragma unroll
    for (int i = 0; i < 4; ++i)
#pragma unroll
      for (int nj = 0; nj < 4; ++nj)
        acc[i][nj] = __builtin_amdgcn_mfma_f32_16x16x32_bf16(af[i], bb[nj], acc[i][nj], 0, 0, 0);
    __builtin_amdgcn_s_setprio(0);
    __builtin_amdgcn_s_barrier();
    // ---- ph3: A(hm1,ks1); drain next tile's staging (>=2 phases old)
    readA(af, buf, 1, 1);
    __builtin_amdgcn_s_barrier();
    __builtin_amdgcn_s_setprio(1);
#pragma unroll
    for (int i = 0; i < 4; ++i)
#pragma unroll
      for (int nj = 0; nj < 4; ++nj)
        acc[4 + i][nj] = __builtin_amdgcn_mfma_f32_16x16x32_bf16(af[i], bb[nj], acc[4 + i][nj], 0, 0, 0);
    __builtin_amdgcn_s_setprio(0);
    WAITVM(0);
    __builtin_amdgcn_s_barrier();
  }

  int er = (lane >> 4) * 4;
  int ec = lane & 15;
#pragma unroll
  for (int mi = 0; mi < 8; ++mi) {
    int rb = row0 + wm + mi * 16 + er;
    float scl[4] = {1.f, 1.f, 1.f, 1.f};
    if (rowscale) {
      float4 s4 = *(const float4*)(rowscale + rb);
      scl[0] = s4.x; scl[1] = s4.y; scl[2] = s4.z; scl[3] = s4.w;
    }
#pragma unroll
    for (int nj = 0; nj < 4; ++nj) {
      int cb = col0 + wn + nj * 16 + ec;
      if (outmode == 1) {
        float* Cb = (float*)Cvoid;
#pragma unroll
        for (int reg = 0; reg < 4; ++reg)
          __builtin_nontemporal_store(acc[mi][nj][reg],
                                      &Cb[(size_t)(rb + reg) * ldc + cb]);
        if (mirror) {
#pragma unroll
          for (int reg = 0; reg < 4; ++reg)
            __builtin_nontemporal_store(acc[mi][nj][reg],
                                        &Cb[(size_t)cb * ldc + rb + reg]);
        }
      } else {
        bf16* Cb = (bf16*)Cvoid;
#pragma unroll
        for (int reg = 0; reg < 4; ++reg)
          Cb[(size_t)(rb + reg) * ldc + cb] = (bf16)(acc[mi][nj][reg] * scl[reg]);
      }
    }
  }
}

// fused sim + qkv, 256^2 tiles: grid 240 = 144 sim (36 supertiles/batch,
// upper-tri, mirror off-diag) + 96 qkv (32 row-tiles x 3 col-tiles).
// XCD-affine: batch z on XCD pair (2z, 2z+1).
__global__ __launch_bounds__(512, 2) void gemm_fused256_kernel(
    const bf16* __restrict__ XsN, float* __restrict__ sim,
    int amap_s, int bmap_s,
    const bf16* __restrict__ Wt, bf16* __restrict__ qkv,
    int amap_q, int bmap_q, const float* __restrict__ norms) {
  __shared__ bf16 S[65536];  // 128 KB
  int g = blockIdx.x;
  if (g < 144) {
    int xcd = g & 7;
    int z = xcd >> 1;
    int t = (xcd & 1) * 18 + (g >> 3);
    int by = 0;
    while (t >= 8 - by) { t -= 8 - by; ++by; }
    int bx = by + t;
    gemm_core256(S,
                 XsN + (size_t)z * N * 512 + (size_t)by * 256 * 512,
                 XsN + (size_t)z * N * 512 + (size_t)bx * 256 * 512,
                 sim + (size_t)z * N * N,
                 N, 12, amap_s, bmap_s, by * 256, bx * 256,
                 1, bx != by, nullptr);
  } else {
    int t = g - 144;
    int xcd = t & 7;
    int slot = t >> 3;                 // 0..11
    int by = (xcd >> 1) * 8 + (xcd & 1) * 4 + slot / 3;
    int bx = slot % 3;
    gemm_core256(S,
                 XsN + (size_t)by * 256 * 512,
                 Wt + (size_t)bx * 256 * 512,
                 qkv, 768, 8, amap_q, bmap_q,
                 by * 256, bx * 256, 2, false, norms);
  }
}

// ---------------------------------------------------------------------------
// 128^2 GEMM core (verified rounds 0-2) — kept for the small-ws fallback.
// ---------------------------------------------------------------------------
__device__ __forceinline__ void gemm_core(bf16* As, bf16* Bs,
                                          const bf16* __restrict__ Ab,
                                          const bf16* __restrict__ Bb,
                                          void* __restrict__ Cvoid,
                                          int lda, int ldb, int ldc,
                                          int nsteps, int amap, int bmap,
                                          int row0, int col0,
                                          int outmode, bool mirror,
                                          const float* __restrict__ rowscale) {
  int tid = threadIdx.x;
  int lane = tid & 63;
  int wv = tid >> 6;
  int wm = (wv >> 1) * 64;
  int wn = (wv & 1) * 64;

  int rbase = tid >> 2;
  int gperm = (tid & 3) ^ ((rbase >> 1) & 3);
  const bf16* ga0 = Ab + (size_t)rbase * lda + gperm * 8;
  const bf16* gb0 = Bb + (size_t)rbase * ldb + gperm * 8;
  int ldsoff = tid * 8;

  int fr = lane & 15;
  int G = lane >> 4;

  f32x4 acc[4][4] = {};

  auto issue = [&](int st, int buf) {
    int ch = st >> 3;
    int aoff = (((amap >> (ch * 2)) & 3) << 8) | ((st & 7) << 5);
    int boff = (((bmap >> (ch * 2)) & 3) << 8) | ((st & 7) << 5);
#pragma unroll
    for (int q = 0; q < 2; ++q)
      async_cp16(ga0 + (size_t)q * 64 * lda + aoff, &As[buf * 4096 + ldsoff + q * 2048]);
#pragma unroll
    for (int q = 0; q < 2; ++q)
      async_cp16(gb0 + (size_t)q * 64 * ldb + boff, &Bs[buf * 4096 + ldsoff + q * 2048]);
  };

  issue(0, 0);
  for (int st = 0; st < nsteps; ++st) {
    int buf = st & 1;
    if (st + 1 < nsteps) {
      issue(st + 1, buf ^ 1);
      WAITVM(4);
    } else {
      WAITVM(0);
    }
    __builtin_amdgcn_s_barrier();
    bf16x8 af[4], bfr[4];
#pragma unroll
    for (int mi = 0; mi < 4; ++mi) {
      int r = wm + mi * 16 + fr;
      af[mi] = *(const bf16x8*)&As[buf * 4096 + r * 32 + ((G ^ ((r >> 1) & 3)) << 3)];
    }
#pragma unroll
    for (int nj = 0; nj < 4; ++nj) {
      int r = wn + nj * 16 + fr;
      bfr[nj] = *(const bf16x8*)&Bs[buf * 4096 + r * 32 + ((G ^ ((r >> 1) & 3)) << 3)];
    }
#pragma unroll
    for (int mi = 0; mi < 4; ++mi)
#pragma unroll
      for (int nj = 0; nj < 4; ++nj)
        acc[mi][nj] = __builtin_amdgcn_mfma_f32_16x16x32_bf16(af[mi], bfr[nj], acc[mi][nj], 0, 0, 0);
    __builtin_amdgcn_s_barrier();
  }

  int er = (lane >> 4) * 4;
  int ec = lane & 15;
#pragma unroll
  for (int mi = 0; mi < 4; ++mi) {
    int rb = row0 + wm + mi * 16 + er;
    float scl[4] = {1.f, 1.f, 1.f, 1.f};
    if (rowscale) {
      float4 s4 = *(const float4*)(rowscale + rb);
      scl[0] = s4.x; scl[1] = s4.y; scl[2] = s4.z; scl[3] = s4.w;
    }
#pragma unroll
    for (int nj = 0; nj < 4; ++nj) {
      int cb = col0 + wn + nj * 16 + ec;
      if (outmode == 1) {
        float* Cb = (float*)Cvoid;
#pragma unroll
        for (int reg = 0; reg < 4; ++reg)
          __builtin_nontemporal_store(acc[mi][nj][reg],
                                      &Cb[(size_t)(rb + reg) * ldc + cb]);
        if (mirror) {
#pragma unroll
          for (int reg = 0; reg < 4; ++reg)
            __builtin_nontemporal_store(acc[mi][nj][reg],
                                        &Cb[(size_t)cb * ldc + rb + reg]);
        }
      } else {
        bf16* Cb = (bf16*)Cvoid;
#pragma unroll
        for (int reg = 0; reg < 4; ++reg)
          Cb[(size_t)(rb + reg) * ldc + cb] = (bf16)(acc[mi][nj][reg] * scl[reg]);
      }
    }
  }
}

// sim-only dispatch (small-ws fallback): grid (544)
__global__ __launch_bounds__(256, 4) void gemm_sim_kernel(const bf16* __restrict__ XsN,
                                                          float* __restrict__ sim,
                                                          int amap, int bmap) {
  __shared__ bf16 As[2 * 128 * 32];
  __shared__ bf16 Bs[2 * 128 * 32];
  int g = blockIdx.x;
  int xcd = g & 7;
  int slot = g >> 3;
  int z = xcd >> 1;
  int t = (xcd & 1) * 68 + slot;
  int by = 0;
  while (t >= 16 - by) { t -= 16 - by; ++by; }
  int bx = by + t;
  gemm_core(As, Bs,
            XsN + (size_t)z * N * 512 + (size_t)by * 128 * 512,
            XsN + (size_t)z * N * 512 + (size_t)bx * 128 * 512,
            sim + (size_t)z * N * N,
            512, 512, N, 24, amap, bmap, by * 128, bx * 128,
            1, bx != by, nullptr);
}

// generic qkv dispatch (small-ws fallback): grid (6, 64), bf16 out
__global__ __launch_bounds__(256, 4) void gemm_qkv_kernel(const bf16* __restrict__ XsN,
                                                          const bf16* __restrict__ Wt,
                                                          bf16* __restrict__ qkv,
                                                          int amap, int bmap,
                                                          const float* __restrict__ norms) {
  __shared__ bf16 As[2 * 128 * 32];
  __shared__ bf16 Bs[2 * 128 * 32];
  gemm_core(As, Bs,
            XsN + (size_t)blockIdx.y * 128 * 512,
            Wt + (size_t)blockIdx.x * 128 * 512,
            qkv, 512, 512, 768, 16, amap, bmap,
            blockIdx.y * 128, blockIdx.x * 128, 2, false, norms);
}

// ---------------------------------------------------------------------------
// top-9 per row by 9x extract-max, fused adjacency write.  One wave per row;
// mask pre-zeroed.  Selection set identical to lax.top_k.
// ---------------------------------------------------------------------------
__global__ __launch_bounds__(64) void topk_adj_kernel(const float* __restrict__ sim,
                                                      unsigned* __restrict__ mask) {
  int row = blockIdx.x;
  int lane = threadIdx.x;
  int b = row >> 11, r = row & 2047;
  const float* srow = sim + (size_t)row * N;
  float v[32];
#pragma unroll
  for (int it = 0; it < 8; ++it) {
    float4 q = *(const float4*)(srow + it * 256 + lane * 4);
    v[it * 4 + 0] = q.x; v[it * 4 + 1] = q.y;
    v[it * 4 + 2] = q.z; v[it * 4 + 3] = q.w;
  }
  unsigned removed = 0;
  for (int rs = 0; rs < TOPK; ++rs) {
    float m = -3e38f;
    int mi = 0;
#pragma unroll
    for (int i = 0; i < 32; ++i) {
      float vv = ((removed >> i) & 1u) ? -3e38f : v[i];
      if (vv > m) { m = vv; mi = i; }
    }
    int gidx = ((mi >> 2) << 8) + lane * 4 + (mi & 3);
    for (int off = 32; off; off >>= 1) {
      float om = __shfl_down(m, off);
      int og = __shfl_down(gidx, off);
      if (om > m || (om == m && og < gidx)) { m = om; gidx = og; }
    }
    gidx = __shfl(gidx, 0);
    if (((gidx >> 2) & 63) == lane)
      removed |= 1u << (((gidx >> 8) << 2) | (gidx & 3));
    if (lane == 0) {
      atomicOr(&mask[(size_t)row * 64 + (gidx >> 5)], 1u << (gidx & 31));
      atomicOr(&mask[(((size_t)b << 11) + gidx) * 64 + (r >> 5)], 1u << (r & 31));
    }
  }
}

// ---------------------------------------------------------------------------
// sparse attention: 4 waves/block, one (b,n) row per wave; XCD-aware decode;
// qkv is bf16 [8192][768]; writes bf16-split aos (stride 512).
// ---------------------------------------------------------------------------
__global__ __launch_bounds__(256) void attn_kernel(const bf16* __restrict__ qkv,
                                                   const unsigned* __restrict__ mask,
                                                   bf16* __restrict__ aos) {
  __shared__ float sq[4][256];
  __shared__ unsigned short nbr[4][2048];
  __shared__ int s_nn[4];
  int wv = threadIdx.x >> 6;
  int lane = threadIdx.x & 63;
  int g = blockIdx.x;
  int xcd = g & 7;
  int b = xcd >> 1;
  int tile = (xcd & 1) * 256 + (g >> 3);
  int bn = b * N + tile * 4 + wv;
  if (lane == 0) s_nn[wv] = 0;
  {
    bf16x4 qv = *(const bf16x4*)(qkv + (size_t)bn * 768 + lane * 4);
#pragma unroll
    for (int j = 0; j < 4; ++j) sq[wv][lane * 4 + j] = (float)qv[j];
  }
  __syncthreads();
  unsigned bits = mask[(size_t)bn * (N / 32) + lane];
  while (bits) {
    int bit = __ffs(bits) - 1;
    bits &= bits - 1;
    int p = atomicAdd(&s_nn[wv], 1);
    nbr[wv][p] = (unsigned short)(lane * 32 + bit);
  }
  __syncthreads();
  int nn = s_nn[wv];
  const bf16* base = qkv + (size_t)b * N * 768;
  float acc[4] = {0.f, 0.f, 0.f, 0.f};

  auto score4 = [&](int j, float* s) {
    const bf16* kr = base + (size_t)j * 768 + 256;
#pragma unroll
    for (int h = 0; h < 4; ++h) {
      float a = 0.f;
#pragma unroll
      for (int c = 0; c < DH; c += 8) {
        bf16x8 kk = *(const bf16x8*)(kr + h * DH + c);
#pragma unroll
        for (int t = 0; t < 8; ++t) a += sq[wv][h * DH + c + t] * (float)kk[t];
      }
      s[h] = a * 0.125f;
    }
  };

  if (nn <= 64) {
    float s[4] = {NEG_BIG, NEG_BIG, NEG_BIG, NEG_BIG};
    if (lane < nn) score4(nbr[wv][lane], s);
    float w[4], l[4];
#pragma unroll
    for (int h = 0; h < 4; ++h) {
      float m = s[h];
      for (int off = 32; off; off >>= 1) m = fmaxf(m, __shfl_down(m, off));
      m = __shfl(m, 0);
      float e = (lane < nn) ? __expf(s[h] - m) : 0.f;
      float ls = e;
      for (int off = 32; off; off >>= 1) ls += __shfl_down(ls, off);
      l[h] = __shfl(ls, 0);
      w[h] = e;
    }
    int i = 0;
    for (; i + 4 <= nn; i += 4) {
      int j0 = nbr[wv][i + 0], j1 = nbr[wv][i + 1];
      int j2 = nbr[wv][i + 2], j3 = nbr[wv][i + 3];
      const bf16* p0 = base + (size_t)j0 * 768 + 512;
      const bf16* p1 = base + (size_t)j1 * 768 + 512;
      const bf16* p2 = base + (size_t)j2 * 768 + 512;
      const bf16* p3 = base + (size_t)j3 * 768 + 512;
#pragma unroll
      for (int h = 0; h < 4; ++h) {
        acc[h] += __shfl(w[h], i + 0) * (float)p0[h * DH + lane] +
                  __shfl(w[h], i + 1) * (float)p1[h * DH + lane] +
                  __shfl(w[h], i + 2) * (float)p2[h * DH + lane] +
                  __shfl(w[h], i + 3) * (float)p3[h * DH + lane];
      }
    }
    for (; i < nn; ++i) {
      const bf16* p0 = base + (size_t)nbr[wv][i] * 768 + 512;
#pragma unroll
      for (int h = 0; h < 4; ++h) acc[h] += __shfl(w[h], i) * (float)p0[h * DH + lane];
    }
#pragma unroll
    for (int h = 0; h < 4; ++h) acc[h] /= l[h];
  } else {
    float m[4] = {NEG_BIG, NEG_BIG, NEG_BIG, NEG_BIG};
    for (int i0 = 0; i0 < nn; i0 += 64) {
      float s[4] = {NEG_BIG, NEG_BIG, NEG_BIG, NEG_BIG};
      if (i0 + lane < nn) score4(nbr[wv][i0 + lane], s);
#pragma unroll
      for (int h = 0; h < 4; ++h) m[h] = fmaxf(m[h], s[h]);
    }
#pragma unroll
    for (int h = 0; h < 4; ++h) {
      for (int off = 32; off; off >>= 1) m[h] = fmaxf(m[h], __shfl_down(m[h], off));
      m[h] = __shfl(m[h], 0);
    }
    float l[4] = {0.f, 0.f, 0.f, 0.f};
    for (int i0 = 0; i0 < nn; i0 += 64) {
      float s[4] = {NEG_BIG, NEG_BIG, NEG_BIG, NEG_BIG};
      if (i0 + lane < nn) score4(nbr[wv][i0 + lane], s);
      float e[4];
#pragma unroll
      for (int h = 0; h < 4; ++h) {
        e[h] = (i0 + lane < nn) ? __expf(s[h] - m[h]) : 0.f;
        float ls = e[h];
        for (int off = 32; off; off >>= 1) ls += __shfl_down(ls, off);
        l[h] += __shfl(ls, 0);
      }
      int lim = min(64, nn - i0);
      for (int ii = 0; ii < lim; ++ii) {
        const bf16* p0 = base + (size_t)nbr[wv][i0 + ii] * 768 + 512;
#pragma unroll
        for (int h = 0; h < 4; ++h) acc[h] += __shfl(e[h], ii) * (float)p0[h * DH + lane];
      }
    }
#pragma unroll
    for (int h = 0; h < 4; ++h) acc[h] /= l[h];
  }
#pragma unroll
  for (int h = 0; h < 4; ++h) {
    float a = acc[h];
    bf16 hi = (bf16)a;
    aos[(size_t)bn * 512 + h * DH + lane] = hi;
    aos[(size_t)bn * 512 + 256 + h * DH + lane] = (bf16)(a - (float)hi);
  }
}

// ---------------------------------------------------------------------------
// fused out-projection + bias + residual + LayerNorm -> out.
// 32 rows x 256 cols per block (grid 256 — every CU busy), BK=32, LDS dbuf,
// swizzle key (r>>1)&3 (0 conflicts, round 10).  Per-row LN: 16-lane shuffle
// + 4-wave LDS combine.
// ---------------------------------------------------------------------------
__global__ __launch_bounds__(256) void projln_kernel(const bf16* __restrict__ A,
                                                     const bf16* __restrict__ Bw,
                                                     const float* __restrict__ x,
                                                     const float* __restrict__ bo,
                                                     const float* __restrict__ gamma,
                                                     const float* __restrict__ beta,
                                                     float* __restrict__ out) {
  __shared__ bf16 As[2 * 32 * 32];     // 4 KB
  __shared__ bf16 Bs[2 * 256 * 32];    // 32 KB
  __shared__ float rsum[32][4];
  __shared__ float rsq[32][4];
  int tid = threadIdx.x;
  int lane = tid & 63;
  int wv = tid >> 6;
  int wn = wv * 64;                    // each wave: all 32 rows x 64 cols
  int row0 = blockIdx.x * 32;

  int rt = tid >> 2;                   // B row helper 0..63
  int ra = tid >> 2;                   // A row 0..31 (tid<128)
  int gpa = (tid & 3) ^ ((ra >> 1) & 3);
  const bf16* ga0 = A + (size_t)(row0 + ra) * 512 + gpa * 8;

  int fr = lane & 15;
  int G = lane >> 4;

  f32x4 acc[2][4] = {};

  auto issue = [&](int st, int buf) {
    int aoff = ((st >> 3) << 8) | ((st & 7) << 5);  // A: ch0 h, ch1 m
    int boff = (st & 7) << 5;                       // B: h only
    if (tid < 128)
      async_cp16(ga0 + aoff, &As[buf * 1024 + tid * 8]);
#pragma unroll
    for (int q = 0; q < 4; ++q) {
      int rb = q * 64 + rt;
      int gpb = (tid & 3) ^ ((rb >> 1) & 3);
      async_cp16(Bw + (size_t)rb * 512 + gpb * 8 + boff,
                 &Bs[buf * 8192 + (q * 256 + tid) * 8]);
    }
  };

  issue(0, 0);
  for (int st = 0; st < 16; ++st) {
    int buf = st & 1;
    if (st + 1 < 16) {
      issue(st + 1, buf ^ 1);
      WAITVM(4);  // waves 2-3: exactly st retired; waves 0-1: slightly stricter
    } else {
      WAITVM(0);
    }
    __builtin_amdgcn_s_barrier();
    bf16x8 af[2], bfr[4];
#pragma unroll
    for (int mi = 0; mi < 2; ++mi) {
      int r = mi * 16 + fr;
      af[mi] = *(const bf16x8*)&As[buf * 1024 + r * 32 + ((G ^ ((r >> 1) & 3)) << 3)];
    }
#pragma unroll
    for (int nj = 0; nj < 4; ++nj) {
      int r = wn + nj * 16 + fr;
      bfr[nj] = *(const bf16x8*)&Bs[buf * 8192 + r * 32 + ((G ^ ((r >> 1) & 3)) << 3)];
    }
#pragma unroll
    for (int mi = 0; mi < 2; ++mi)
#pragma unroll
      for (int nj = 0; nj < 4; ++nj)
        acc[mi][nj] = __builtin_amdgcn_mfma_f32_16x16x32_bf16(af[mi], bfr[nj], acc[mi][nj], 0, 0, 0);
    __builtin_amdgcn_s_barrier();
  }

  int er = (lane >> 4) * 4;
  int ec = lane & 15;
  float bo_c[4], ga_c[4], be_c[4];
#pragma unroll
  for (int nj = 0; nj < 4; ++nj) {
    int c = wn + nj * 16 + ec;
    bo_c[nj] = bo[c]; ga_c[nj] = gamma[c]; be_c[nj] = beta[c];
  }
#pragma unroll
  for (int mi = 0; mi < 2; ++mi)
#pragma unroll
    for (int reg = 0; reg < 4; ++reg) {
      int rloc = mi * 16 + er + reg;
      const float* xr = x + (size_t)(row0 + rloc) * D;
      float su = 0.f, s2 = 0.f;
#pragma unroll
      for (int nj = 0; nj < 4; ++nj) {
        float u = acc[mi][nj][reg] + bo_c[nj] + xr[wn + nj * 16 + ec];
        su += u; s2 += u * u;
      }
#pragma unroll
      for (int m = 1; m <= 8; m <<= 1) {
        su += __shfl_xor(su, m);
        s2 += __shfl_xor(s2, m);
      }
      if (ec == 0) { rsum[rloc][wv] = su; rsq[rloc][wv] = s2; }
    }
  __syncthreads();
#pragma unroll
  for (int mi = 0; mi < 2; ++mi)
#pragma unroll
    for (int reg = 0; reg < 4; ++reg) {
      int rloc = mi * 16 + er + reg;
      float s = rsum[rloc][0] + rsum[rloc][1] + rsum[rloc][2] + rsum[rloc][3];
      float q2 = rsq[rloc][0] + rsq[rloc][1] + rsq[rloc][2] + rsq[rloc][3];
      float mean = s * (1.0f / D);
      float var = q2 * (1.0f / D) - mean * mean;
      float rstd = rsqrtf(var + 1e-5f);
      const float* xr = x + (size_t)(row0 + rloc) * D;
      float* orow = out + (size_t)(row0 + rloc) * D;
#pragma unroll
      for (int nj = 0; nj < 4; ++nj) {
        float u = acc[mi][nj][reg] + bo_c[nj] + xr[wn + nj * 16 + ec];
        orow[wn + nj * 16 + ec] = (u - mean) * rstd * ga_c[nj] + be_c[nj];
      }
    }
}

// ---------------------------------------------------------------------------
// Workspace.  Common: XsN [0,8.39M) | sim [12.58M,79.69M) | norms@79.69M
//                     mask@79.99M | Wt@82.08M (ends 83,132,416)
// BIG (ws >= 125 MB; fill shows 256 MiB): qkv(bf16)@83.13M | aos@95.72M
// SMALL: qkv@12.58M, aos@37.75M (dead-sim region, written after topk)
// ---------------------------------------------------------------------------
extern "C" void kernel_launch(void* const* d_in, const int* in_sizes, int n_in,
                              void* d_out, int out_size, void* d_ws, size_t ws_size,
                              hipStream_t stream) {
  const float* x     = (const float*)d_in[0];
  const float* Wq    = (const float*)d_in[1];
  const float* Wk    = (const float*)d_in[2];
  const float* Wv    = (const float*)d_in[3];
  const float* Wo    = (const float*)d_in[4];
  const float* bo    = (const float*)d_in[5];
  const float* gamma = (const float*)d_in[6];
  const float* beta  = (const float*)d_in[7];
  float* out = (float*)d_out;

  char* ws = (char*)d_ws;
  bf16* XsN      = (bf16*)(ws);
  float* sim     = (float*)(ws + 12582912);
  float* norms   = (float*)(ws + 79691776);
  unsigned* mask = (unsigned*)(ws + 79986688);
  bf16* Wt       = (bf16*)(ws + 82083840);

  bool big = ws_size >= (size_t)125000000;
  bf16* qkv = (bf16*)(ws + (big ? 83132416 : 12582912));
  bf16* aos = (bf16*)(ws + (big ? 95715328 : 37748736));

  const int AMAP_SIM = PK6(0, 0, 1, 0, 0, 0);  // hh + hm + mh
  const int BMAP_SIM = PK6(0, 1, 0, 0, 0, 0);
  const int AMAP_2T  = PK3(0, 1, 0);           // (h+m)_A · h_B
  const int BMAP_2T  = PK3(0, 0, 1);

  prep_kernel<<<9344, 64, 0, stream>>>(x, Wq, Wk, Wv, Wo, XsN, Wt, norms,
                                       (uint4*)mask);

  if (big) {
    gemm_fused256_kernel<<<240, 512, 0, stream>>>(
        XsN, sim, AMAP_SIM, BMAP_SIM, Wt, qkv, AMAP_2T, BMAP_2T, norms);
    topk_adj_kernel<<<BATCH * N, 64, 0, stream>>>(sim, mask);
  } else {
    gemm_sim_kernel<<<544, 256, 0, stream>>>(XsN, sim, AMAP_SIM, BMAP_SIM);
    topk_adj_kernel<<<BATCH * N, 64, 0, stream>>>(sim, mask);
    gemm_qkv_kernel<<<dim3(6, 64), 256, 0, stream>>>(XsN, Wt, qkv,
                                                     AMAP_2T, BMAP_2T, norms);
  }

  attn_kernel<<<(BATCH * N) / 4, 256, 0, stream>>>(qkv, mask, aos);

  projln_kernel<<<256, 256, 0, stream>>>(aos, Wt + (size_t)768 * 512,
                                         x, bo, gamma, beta, out);
}

// Round 5
// 187.759 us; speedup vs baseline: 1.0111x; 1.0111x over previous
//
#include <hip/hip_runtime.h>
#include <hip/hip_bf16.h>
#include <math.h>

#define BATCH 4
#define N 2048
#define D 256
#define NH 4
#define DH 64
#define TOPK 9
#define NEG_BIG -1e30f

typedef __bf16 bf16;
typedef __bf16 bf16x4 __attribute__((ext_vector_type(4)));
typedef __bf16 bf16x8 __attribute__((ext_vector_type(8)));
typedef float f32x4 __attribute__((ext_vector_type(4)));

#define PK3(a,b,c) ((a) | ((b) << 2) | ((c) << 4))
#define PK6(a,b,c,d,e,f) ((a) | ((b) << 2) | ((c) << 4) | ((d) << 6) | ((e) << 8) | ((f) << 10))

// s_waitcnt with ONLY vmcnt=N. gfx9 encoding: vmcnt[3:0]@0, expcnt@4,
// lgkmcnt@8, vmcnt[5:4]@14.
#define WAITVM(Nc) __builtin_amdgcn_s_waitcnt((((Nc) & 0xf)) | (7u << 4) | (0xfu << 8) | ((((unsigned)(Nc)) >> 4) << 14))

__device__ __forceinline__ void async_cp16(const bf16* g, const bf16* l) {
  __builtin_amdgcn_global_load_lds(
      (const __attribute__((address_space(1))) void*)(uintptr_t)g,
      (__attribute__((address_space(3))) void*)(uintptr_t)l, 16, 0, 0);
}

// ---------------------------------------------------------------------------
// prep: blk<8192: x -> XsN (L2-norm, 2-way split h/m, stride 512) + norms
//       blk<9216: W{q,k,v,o} -> Wt (transpose + 2-way split)
//       else (128 blks): zero the 2 MB adjacency mask
// ---------------------------------------------------------------------------
__global__ __launch_bounds__(64) void prep_kernel(const float* __restrict__ x,
                                                  const float* __restrict__ Wq,
                                                  const float* __restrict__ Wk,
                                                  const float* __restrict__ Wv,
                                                  const float* __restrict__ Wo,
                                                  bf16* __restrict__ XsN,
                                                  bf16* __restrict__ Wt,
                                                  float* __restrict__ norms,
                                                  uint4* __restrict__ mask4) {
  int blk = blockIdx.x;
  int lane = threadIdx.x;
  if (blk < 8192) {
    float4 v = *(const float4*)(x + (size_t)blk * D + lane * 4);
    float ss = v.x * v.x + v.y * v.y + v.z * v.z + v.w * v.w;
    for (int off = 32; off; off >>= 1) ss += __shfl_down(ss, off);
    ss = __shfl(ss, 0);
    float nrm = fmaxf(sqrtf(ss), 1e-12f);
    if (lane == 0) norms[blk] = nrm;
    float sc = 1.0f / nrm;
    float xs[4] = {v.x * sc, v.y * sc, v.z * sc, v.w * sc};
    bf16* o = XsN + (size_t)blk * 512 + lane * 4;
#pragma unroll
    for (int j = 0; j < 4; ++j) {
      float xv = xs[j];
      bf16 h = (bf16)xv;
      o[j] = h;
      o[256 + j] = (bf16)(xv - (float)h);
    }
  } else if (blk < 9216) {
    int jj = blk - 8192;
    const float* W = (jj < 256) ? Wq : (jj < 512) ? Wk : (jj < 768) ? Wv : Wo;
    int j = jj & 255;
    bf16* dst = Wt + (size_t)jj * 512;
    for (int k = lane; k < 256; k += 64) {
      float w = W[(size_t)k * D + j];
      bf16 h = (bf16)w;
      dst[k] = h;
      dst[256 + k] = (bf16)(w - (float)h);
    }
  } else {
    int base = (blk - 9216) * 1024 + lane;
#pragma unroll
    for (int t = 0; t < 16; ++t)
      mask4[base + t * 64] = make_uint4(0, 0, 0, 0);
  }
}

// ---------------------------------------------------------------------------
// 128x256 4-wave GEMM core (round 3/4).  Rationale: round-2 (128^2, 4 blk/CU)
// had overlap but 16-MFMA-per-barrier; 256^2 (1 blk/CU) had 64-MFMA clusters
// but ZERO overlap (idle CUs, serialized 512KB epilogue).  Midpoint: BK=32,
// 48KB LDS dbuf -> 2 blocks/CU co-resident, 32 MFMA per wave per
// barrier-pair, 480-block grid.  Counted WAITVM(6) = one tile in flight.
// Swizzle (r>>1)&3 on 4x16B slots (0 conflicts, proven).  K-slice order
// identical to rounds 0-2 -> output bit-identical.
// outmode 1: fp32 nontemporal + optional mirror (sim; mirror = f32x4 vector,
//            NOT HIP float4 — __builtin_nontemporal_store rejects the class).
// outmode 2: bf16 with per-row norm rescale (qkv).
// ---------------------------------------------------------------------------
__device__ __forceinline__ void gemm_core128x256(bf16* As, bf16* Bs,
                                                 const bf16* __restrict__ Ab,
                                                 const bf16* __restrict__ Bb,
                                                 void* __restrict__ Cvoid,
                                                 int ldc, int nsteps,
                                                 int amap, int bmap,
                                                 int row0, int col0,
                                                 int outmode, bool mirror,
                                                 const float* __restrict__ rowscale) {
  int tid = threadIdx.x;
  int lane = tid & 63;
  int wv = tid >> 6;            // 4 waves: 2M x 2N
  int wm = (wv >> 1) * 64;      // wave rows: 64 of 128
  int wn = (wv & 1) * 128;      // wave cols: 128 of 256
  int fr = lane & 15;
  int G = lane >> 4;            // k-slot 0..3 (8 bf16 each)

  f32x4 acc[4][8] = {};

  auto issue = [&](int st, int buf) {
    int ch = st >> 3;                                        // 256-K chunk
    int aoff = (((amap >> (ch * 2)) & 3) << 8) | ((st & 7) << 5);
    int boff = (((bmap >> (ch * 2)) & 3) << 8) | ((st & 7) << 5);
    // A: 128x32 = 512 16B-slots, 2/thread
#pragma unroll
    for (int q = 0; q < 2; ++q) {
      int s = q * 256 + tid;
      int r = s >> 2, sl = s & 3;
      async_cp16(Ab + (size_t)r * 512 + ((sl ^ ((r >> 1) & 3)) << 3) + aoff,
                 &As[buf * 4096 + s * 8]);
    }
    // B: 256x32 = 1024 16B-slots, 4/thread
#pragma unroll
    for (int q = 0; q < 4; ++q) {
      int s = q * 256 + tid;
      int r = s >> 2, sl = s & 3;
      async_cp16(Bb + (size_t)r * 512 + ((sl ^ ((r >> 1) & 3)) << 3) + boff,
                 &Bs[buf * 8192 + s * 8]);
    }
  };

  issue(0, 0);
  for (int st = 0; st < nsteps; ++st) {
    int buf = st & 1;
    if (st + 1 < nsteps) {
      issue(st + 1, buf ^ 1);
      WAITVM(6);        // exactly the 6 just-issued outstanding; tile st landed
    } else {
      WAITVM(0);
    }
    __builtin_amdgcn_s_barrier();
    bf16x8 af[4], bfr[8];
#pragma unroll
    for (int mi = 0; mi < 4; ++mi) {
      int r = wm + mi * 16 + fr;
      af[mi] = *(const bf16x8*)&As[buf * 4096 + r * 32 + ((G ^ ((r >> 1) & 3)) << 3)];
    }
#pragma unroll
    for (int nj = 0; nj < 8; ++nj) {
      int r = wn + nj * 16 + fr;
      bfr[nj] = *(const bf16x8*)&Bs[buf * 8192 + r * 32 + ((G ^ ((r >> 1) & 3)) << 3)];
    }
    __builtin_amdgcn_s_setprio(1);
#pragma unroll
    for (int mi = 0; mi < 4; ++mi)
#pragma unroll
      for (int nj = 0; nj < 8; ++nj)
        acc[mi][nj] = __builtin_amdgcn_mfma_f32_16x16x32_bf16(af[mi], bfr[nj], acc[mi][nj], 0, 0, 0);
    __builtin_amdgcn_s_setprio(0);
    __builtin_amdgcn_s_barrier();
  }

  int er = (lane >> 4) * 4;
  int ec = lane & 15;
#pragma unroll
  for (int mi = 0; mi < 4; ++mi) {
    int rb = row0 + wm + mi * 16 + er;
    float scl[4] = {1.f, 1.f, 1.f, 1.f};
    if (rowscale) {
      float4 s4 = *(const float4*)(rowscale + rb);
      scl[0] = s4.x; scl[1] = s4.y; scl[2] = s4.z; scl[3] = s4.w;
    }
#pragma unroll
    for (int nj = 0; nj < 8; ++nj) {
      int cb = col0 + wn + nj * 16 + ec;
      if (outmode == 1) {
        float* Cb = (float*)Cvoid;
#pragma unroll
        for (int reg = 0; reg < 4; ++reg)
          __builtin_nontemporal_store(acc[mi][nj][reg],
                                      &Cb[(size_t)(rb + reg) * ldc + cb]);
        if (mirror) {
          // mirrored: 4 consecutive rows -> contiguous col-major addresses;
          // acc[mi][nj] is a clang ext_vector (f32x4) — valid for the builtin.
          __builtin_nontemporal_store(acc[mi][nj],
                                      (f32x4*)&Cb[(size_t)cb * ldc + rb]);
        }
      } else {
        bf16* Cb = (bf16*)Cvoid;
#pragma unroll
        for (int reg = 0; reg < 4; ++reg)
          Cb[(size_t)(rb + reg) * ldc + cb] = (bf16)(acc[mi][nj][reg] * scl[reg]);
      }
    }
  }
}

// fused sim + qkv, 128x256 tiles: grid 480 = 288 sim (36 upper supertiles/
// batch x 2 row-halves) + 192 qkv (16 row-tiles/batch x 3 col-tiles).
// XCD-affine: batch z on XCD pair (2z, 2z+1); both halves of a supertile on
// the same XCD consecutively (B-panel L2 reuse).
__global__ __launch_bounds__(256, 2) void gemm_fused128x256_kernel(
    const bf16* __restrict__ XsN, float* __restrict__ sim,
    int amap_s, int bmap_s,
    const bf16* __restrict__ Wt, bf16* __restrict__ qkv,
    int amap_q, int bmap_q, const float* __restrict__ norms) {
  __shared__ bf16 As[2 * 128 * 32];   // 16 KB
  __shared__ bf16 Bs[2 * 256 * 32];   // 32 KB
  int g = blockIdx.x;
  if (g < 288) {
    int xcd = g & 7;
    int z = xcd >> 1;
    int t = (xcd & 1) * 36 + (g >> 3);   // 0..71 within batch
    int half = t & 1;
    int u = t >> 1;                      // supertile 0..35
    int by = 0;
    while (u >= 8 - by) { u -= 8 - by; ++by; }
    int bx = by + u;
    int row0 = by * 256 + half * 128;
    int col0 = bx * 256;
    gemm_core128x256(As, Bs,
                     XsN + (size_t)z * N * 512 + (size_t)row0 * 512,
                     XsN + (size_t)z * N * 512 + (size_t)col0 * 512,
                     sim + (size_t)z * N * N,
                     N, 24, amap_s, bmap_s, row0, col0,
                     1, bx != by, nullptr);
  } else {
    int t = g - 288;
    int xcd = t & 7;
    int slot = t >> 3;                   // 0..23
    int z = xcd >> 1;
    int by = z * 16 + (xcd & 1) * 8 + slot / 3;  // 0..63 global 128-row tiles
    int bx = slot % 3;
    gemm_core128x256(As, Bs,
                     XsN + (size_t)by * 128 * 512,
                     Wt + (size_t)bx * 256 * 512,
                     qkv, 768, 16, amap_q, bmap_q,
                     by * 128, bx * 256, 2, false, norms);
  }
}

// ---------------------------------------------------------------------------
// 128^2 GEMM core (verified rounds 0-2) — kept for the small-ws fallback.
// ---------------------------------------------------------------------------
__device__ __forceinline__ void gemm_core(bf16* As, bf16* Bs,
                                          const bf16* __restrict__ Ab,
                                          const bf16* __restrict__ Bb,
                                          void* __restrict__ Cvoid,
                                          int lda, int ldb, int ldc,
                                          int nsteps, int amap, int bmap,
                                          int row0, int col0,
                                          int outmode, bool mirror,
                                          const float* __restrict__ rowscale) {
  int tid = threadIdx.x;
  int lane = tid & 63;
  int wv = tid >> 6;
  int wm = (wv >> 1) * 64;
  int wn = (wv & 1) * 64;

  int rbase = tid >> 2;
  int gperm = (tid & 3) ^ ((rbase >> 1) & 3);
  const bf16* ga0 = Ab + (size_t)rbase * lda + gperm * 8;
  const bf16* gb0 = Bb + (size_t)rbase * ldb + gperm * 8;
  int ldsoff = tid * 8;

  int fr = lane & 15;
  int G = lane >> 4;

  f32x4 acc[4][4] = {};

  auto issue = [&](int st, int buf) {
    int ch = st >> 3;
    int aoff = (((amap >> (ch * 2)) & 3) << 8) | ((st & 7) << 5);
    int boff = (((bmap >> (ch * 2)) & 3) << 8) | ((st & 7) << 5);
#pragma unroll
    for (int q = 0; q < 2; ++q)
      async_cp16(ga0 + (size_t)q * 64 * lda + aoff, &As[buf * 4096 + ldsoff + q * 2048]);
#pragma unroll
    for (int q = 0; q < 2; ++q)
      async_cp16(gb0 + (size_t)q * 64 * ldb + boff, &Bs[buf * 4096 + ldsoff + q * 2048]);
  };

  issue(0, 0);
  for (int st = 0; st < nsteps; ++st) {
    int buf = st & 1;
    if (st + 1 < nsteps) {
      issue(st + 1, buf ^ 1);
      WAITVM(4);
    } else {
      WAITVM(0);
    }
    __builtin_amdgcn_s_barrier();
    bf16x8 af[4], bfr[4];
#pragma unroll
    for (int mi = 0; mi < 4; ++mi) {
      int r = wm + mi * 16 + fr;
      af[mi] = *(const bf16x8*)&As[buf * 4096 + r * 32 + ((G ^ ((r >> 1) & 3)) << 3)];
    }
#pragma unroll
    for (int nj = 0; nj < 4; ++nj) {
      int r = wn + nj * 16 + fr;
      bfr[nj] = *(const bf16x8*)&Bs[buf * 4096 + r * 32 + ((G ^ ((r >> 1) & 3)) << 3)];
    }
#pragma unroll
    for (int mi = 0; mi < 4; ++mi)
#pragma unroll
      for (int nj = 0; nj < 4; ++nj)
        acc[mi][nj] = __builtin_amdgcn_mfma_f32_16x16x32_bf16(af[mi], bfr[nj], acc[mi][nj], 0, 0, 0);
    __builtin_amdgcn_s_barrier();
  }

  int er = (lane >> 4) * 4;
  int ec = lane & 15;
#pragma unroll
  for (int mi = 0; mi < 4; ++mi) {
    int rb = row0 + wm + mi * 16 + er;
    float scl[4] = {1.f, 1.f, 1.f, 1.f};
    if (rowscale) {
      float4 s4 = *(const float4*)(rowscale + rb);
      scl[0] = s4.x; scl[1] = s4.y; scl[2] = s4.z; scl[3] = s4.w;
    }
#pragma unroll
    for (int nj = 0; nj < 4; ++nj) {
      int cb = col0 + wn + nj * 16 + ec;
      if (outmode == 1) {
        float* Cb = (float*)Cvoid;
#pragma unroll
        for (int reg = 0; reg < 4; ++reg)
          __builtin_nontemporal_store(acc[mi][nj][reg],
                                      &Cb[(size_t)(rb + reg) * ldc + cb]);
        if (mirror) {
#pragma unroll
          for (int reg = 0; reg < 4; ++reg)
            __builtin_nontemporal_store(acc[mi][nj][reg],
                                        &Cb[(size_t)cb * ldc + rb + reg]);
        }
      } else {
        bf16* Cb = (bf16*)Cvoid;
#pragma unroll
        for (int reg = 0; reg < 4; ++reg)
          Cb[(size_t)(rb + reg) * ldc + cb] = (bf16)(acc[mi][nj][reg] * scl[reg]);
      }
    }
  }
}

// sim-only dispatch (small-ws fallback): grid (544)
__global__ __launch_bounds__(256, 4) void gemm_sim_kernel(const bf16* __restrict__ XsN,
                                                          float* __restrict__ sim,
                                                          int amap, int bmap) {
  __shared__ bf16 As[2 * 128 * 32];
  __shared__ bf16 Bs[2 * 128 * 32];
  int g = blockIdx.x;
  int xcd = g & 7;
  int slot = g >> 3;
  int z = xcd >> 1;
  int t = (xcd & 1) * 68 + slot;
  int by = 0;
  while (t >= 16 - by) { t -= 16 - by; ++by; }
  int bx = by + t;
  gemm_core(As, Bs,
            XsN + (size_t)z * N * 512 + (size_t)by * 128 * 512,
            XsN + (size_t)z * N * 512 + (size_t)bx * 128 * 512,
            sim + (size_t)z * N * N,
            512, 512, N, 24, amap, bmap, by * 128, bx * 128,
            1, bx != by, nullptr);
}

// generic qkv dispatch (small-ws fallback): grid (6, 64), bf16 out
__global__ __launch_bounds__(256, 4) void gemm_qkv_kernel(const bf16* __restrict__ XsN,
                                                          const bf16* __restrict__ Wt,
                                                          bf16* __restrict__ qkv,
                                                          int amap, int bmap,
                                                          const float* __restrict__ norms) {
  __shared__ bf16 As[2 * 128 * 32];
  __shared__ bf16 Bs[2 * 128 * 32];
  gemm_core(As, Bs,
            XsN + (size_t)blockIdx.y * 128 * 512,
            Wt + (size_t)blockIdx.x * 128 * 512,
            qkv, 512, 512, 768, 16, amap, bmap,
            blockIdx.y * 128, blockIdx.x * 128, 2, false, norms);
}

// ---------------------------------------------------------------------------
// top-9 per row by 9x extract-max, fused adjacency write.  One wave per row;
// mask pre-zeroed.  Selection set identical to lax.top_k.
// ---------------------------------------------------------------------------
__global__ __launch_bounds__(64) void topk_adj_kernel(const float* __restrict__ sim,
                                                      unsigned* __restrict__ mask) {
  int row = blockIdx.x;
  int lane = threadIdx.x;
  int b = row >> 11, r = row & 2047;
  const float* srow = sim + (size_t)row * N;
  float v[32];
#pragma unroll
  for (int it = 0; it < 8; ++it) {
    float4 q = *(const float4*)(srow + it * 256 + lane * 4);
    v[it * 4 + 0] = q.x; v[it * 4 + 1] = q.y;
    v[it * 4 + 2] = q.z; v[it * 4 + 3] = q.w;
  }
  unsigned removed = 0;
  for (int rs = 0; rs < TOPK; ++rs) {
    float m = -3e38f;
    int mi = 0;
#pragma unroll
    for (int i = 0; i < 32; ++i) {
      float vv = ((removed >> i) & 1u) ? -3e38f : v[i];
      if (vv > m) { m = vv; mi = i; }
    }
    int gidx = ((mi >> 2) << 8) + lane * 4 + (mi & 3);
    for (int off = 32; off; off >>= 1) {
      float om = __shfl_down(m, off);
      int og = __shfl_down(gidx, off);
      if (om > m || (om == m && og < gidx)) { m = om; gidx = og; }
    }
    gidx = __shfl(gidx, 0);
    if (((gidx >> 2) & 63) == lane)
      removed |= 1u << (((gidx >> 8) << 2) | (gidx & 3));
    if (lane == 0) {
      atomicOr(&mask[(size_t)row * 64 + (gidx >> 5)], 1u << (gidx & 31));
      atomicOr(&mask[(((size_t)b << 11) + gidx) * 64 + (r >> 5)], 1u << (r & 31));
    }
  }
}

// ---------------------------------------------------------------------------
// sparse attention: 4 waves/block, one (b,n) row per wave; XCD-aware decode;
// qkv is bf16 [8192][768]; writes bf16-split aos (stride 512).
// ---------------------------------------------------------------------------
__global__ __launch_bounds__(256) void attn_kernel(const bf16* __restrict__ qkv,
                                                   const unsigned* __restrict__ mask,
                                                   bf16* __restrict__ aos) {
  __shared__ float sq[4][256];
  __shared__ unsigned short nbr[4][2048];
  __shared__ int s_nn[4];
  int wv = threadIdx.x >> 6;
  int lane = threadIdx.x & 63;
  int g = blockIdx.x;
  int xcd = g & 7;
  int b = xcd >> 1;
  int tile = (xcd & 1) * 256 + (g >> 3);
  int bn = b * N + tile * 4 + wv;
  if (lane == 0) s_nn[wv] = 0;
  {
    bf16x4 qv = *(const bf16x4*)(qkv + (size_t)bn * 768 + lane * 4);
#pragma unroll
    for (int j = 0; j < 4; ++j) sq[wv][lane * 4 + j] = (float)qv[j];
  }
  __syncthreads();
  unsigned bits = mask[(size_t)bn * (N / 32) + lane];
  while (bits) {
    int bit = __ffs(bits) - 1;
    bits &= bits - 1;
    int p = atomicAdd(&s_nn[wv], 1);
    nbr[wv][p] = (unsigned short)(lane * 32 + bit);
  }
  __syncthreads();
  int nn = s_nn[wv];
  const bf16* base = qkv + (size_t)b * N * 768;
  float acc[4] = {0.f, 0.f, 0.f, 0.f};

  auto score4 = [&](int j, float* s) {
    const bf16* kr = base + (size_t)j * 768 + 256;
#pragma unroll
    for (int h = 0; h < 4; ++h) {
      float a = 0.f;
#pragma unroll
      for (int c = 0; c < DH; c += 8) {
        bf16x8 kk = *(const bf16x8*)(kr + h * DH + c);
#pragma unroll
        for (int t = 0; t < 8; ++t) a += sq[wv][h * DH + c + t] * (float)kk[t];
      }
      s[h] = a * 0.125f;
    }
  };

  if (nn <= 64) {
    float s[4] = {NEG_BIG, NEG_BIG, NEG_BIG, NEG_BIG};
    if (lane < nn) score4(nbr[wv][lane], s);
    float w[4], l[4];
#pragma unroll
    for (int h = 0; h < 4; ++h) {
      float m = s[h];
      for (int off = 32; off; off >>= 1) m = fmaxf(m, __shfl_down(m, off));
      m = __shfl(m, 0);
      float e = (lane < nn) ? __expf(s[h] - m) : 0.f;
      float ls = e;
      for (int off = 32; off; off >>= 1) ls += __shfl_down(ls, off);
      l[h] = __shfl(ls, 0);
      w[h] = e;
    }
    int i = 0;
    for (; i + 4 <= nn; i += 4) {
      int j0 = nbr[wv][i + 0], j1 = nbr[wv][i + 1];
      int j2 = nbr[wv][i + 2], j3 = nbr[wv][i + 3];
      const bf16* p0 = base + (size_t)j0 * 768 + 512;
      const bf16* p1 = base + (size_t)j1 * 768 + 512;
      const bf16* p2 = base + (size_t)j2 * 768 + 512;
      const bf16* p3 = base + (size_t)j3 * 768 + 512;
#pragma unroll
      for (int h = 0; h < 4; ++h) {
        acc[h] += __shfl(w[h], i + 0) * (float)p0[h * DH + lane] +
                  __shfl(w[h], i + 1) * (float)p1[h * DH + lane] +
                  __shfl(w[h], i + 2) * (float)p2[h * DH + lane] +
                  __shfl(w[h], i + 3) * (float)p3[h * DH + lane];
      }
    }
    for (; i < nn; ++i) {
      const bf16* p0 = base + (size_t)nbr[wv][i] * 768 + 512;
#pragma unroll
      for (int h = 0; h < 4; ++h) acc[h] += __shfl(w[h], i) * (float)p0[h * DH + lane];
    }
#pragma unroll
    for (int h = 0; h < 4; ++h) acc[h] /= l[h];
  } else {
    float m[4] = {NEG_BIG, NEG_BIG, NEG_BIG, NEG_BIG};
    for (int i0 = 0; i0 < nn; i0 += 64) {
      float s[4] = {NEG_BIG, NEG_BIG, NEG_BIG, NEG_BIG};
      if (i0 + lane < nn) score4(nbr[wv][i0 + lane], s);
#pragma unroll
      for (int h = 0; h < 4; ++h) m[h] = fmaxf(m[h], s[h]);
    }
#pragma unroll
    for (int h = 0; h < 4; ++h) {
      for (int off = 32; off; off >>= 1) m[h] = fmaxf(m[h], __shfl_down(m[h], off));
      m[h] = __shfl(m[h], 0);
    }
    float l[4] = {0.f, 0.f, 0.f, 0.f};
    for (int i0 = 0; i0 < nn; i0 += 64) {
      float s[4] = {NEG_BIG, NEG_BIG, NEG_BIG, NEG_BIG};
      if (i0 + lane < nn) score4(nbr[wv][i0 + lane], s);
      float e[4];
#pragma unroll
      for (int h = 0; h < 4; ++h) {
        e[h] = (i0 + lane < nn) ? __expf(s[h] - m[h]) : 0.f;
        float ls = e[h];
        for (int off = 32; off; off >>= 1) ls += __shfl_down(ls, off);
        l[h] += __shfl(ls, 0);
      }
      int lim = min(64, nn - i0);
      for (int ii = 0; ii < lim; ++ii) {
        const bf16* p0 = base + (size_t)nbr[wv][i0 + ii] * 768 + 512;
#pragma unroll
        for (int h = 0; h < 4; ++h) acc[h] += __shfl(e[h], ii) * (float)p0[h * DH + lane];
      }
    }
#pragma unroll
    for (int h = 0; h < 4; ++h) acc[h] /= l[h];
  }
#pragma unroll
  for (int h = 0; h < 4; ++h) {
    float a = acc[h];
    bf16 hi = (bf16)a;
    aos[(size_t)bn * 512 + h * DH + lane] = hi;
    aos[(size_t)bn * 512 + 256 + h * DH + lane] = (bf16)(a - (float)hi);
  }
}

// ---------------------------------------------------------------------------
// fused out-projection + bias + residual + LayerNorm -> out.
// 32 rows x 256 cols per block (grid 256 — every CU busy), BK=32, LDS dbuf,
// swizzle key (r>>1)&3 (0 conflicts, round 10).  Per-row LN: 16-lane shuffle
// + 4-wave LDS combine.
// ---------------------------------------------------------------------------
__global__ __launch_bounds__(256) void projln_kernel(const bf16* __restrict__ A,
                                                     const bf16* __restrict__ Bw,
                                                     const float* __restrict__ x,
                                                     const float* __restrict__ bo,
                                                     const float* __restrict__ gamma,
                                                     const float* __restrict__ beta,
                                                     float* __restrict__ out) {
  __shared__ bf16 As[2 * 32 * 32];     // 4 KB
  __shared__ bf16 Bs[2 * 256 * 32];    // 32 KB
  __shared__ float rsum[32][4];
  __shared__ float rsq[32][4];
  int tid = threadIdx.x;
  int lane = tid & 63;
  int wv = tid >> 6;
  int wn = wv * 64;                    // each wave: all 32 rows x 64 cols
  int row0 = blockIdx.x * 32;

  int rt = tid >> 2;                   // B row helper 0..63
  int ra = tid >> 2;                   // A row 0..31 (tid<128)
  int gpa = (tid & 3) ^ ((ra >> 1) & 3);
  const bf16* ga0 = A + (size_t)(row0 + ra) * 512 + gpa * 8;

  int fr = lane & 15;
  int G = lane >> 4;

  f32x4 acc[2][4] = {};

  auto issue = [&](int st, int buf) {
    int aoff = ((st >> 3) << 8) | ((st & 7) << 5);  // A: ch0 h, ch1 m
    int boff = (st & 7) << 5;                       // B: h only
    if (tid < 128)
      async_cp16(ga0 + aoff, &As[buf * 1024 + tid * 8]);
#pragma unroll
    for (int q = 0; q < 4; ++q) {
      int rb = q * 64 + rt;
      int gpb = (tid & 3) ^ ((rb >> 1) & 3);
      async_cp16(Bw + (size_t)rb * 512 + gpb * 8 + boff,
                 &Bs[buf * 8192 + (q * 256 + tid) * 8]);
    }
  };

  issue(0, 0);
  for (int st = 0; st < 16; ++st) {
    int buf = st & 1;
    if (st + 1 < 16) {
      issue(st + 1, buf ^ 1);
      WAITVM(4);  // waves 2-3: exactly st retired; waves 0-1: slightly stricter
    } else {
      WAITVM(0);
    }
    __builtin_amdgcn_s_barrier();
    bf16x8 af[2], bfr[4];
#pragma unroll
    for (int mi = 0; mi < 2; ++mi) {
      int r = mi * 16 + fr;
      af[mi] = *(const bf16x8*)&As[buf * 1024 + r * 32 + ((G ^ ((r >> 1) & 3)) << 3)];
    }
#pragma unroll
    for (int nj = 0; nj < 4; ++nj) {
      int r = wn + nj * 16 + fr;
      bfr[nj] = *(const bf16x8*)&Bs[buf * 8192 + r * 32 + ((G ^ ((r >> 1) & 3)) << 3)];
    }
#pragma unroll
    for (int mi = 0; mi < 2; ++mi)
#pragma unroll
      for (int nj = 0; nj < 4; ++nj)
        acc[mi][nj] = __builtin_amdgcn_mfma_f32_16x16x32_bf16(af[mi], bfr[nj], acc[mi][nj], 0, 0, 0);
    __builtin_amdgcn_s_barrier();
  }

  int er = (lane >> 4) * 4;
  int ec = lane & 15;
  float bo_c[4], ga_c[4], be_c[4];
#pragma unroll
  for (int nj = 0; nj < 4; ++nj) {
    int c = wn + nj * 16 + ec;
    bo_c[nj] = bo[c]; ga_c[nj] = gamma[c]; be_c[nj] = beta[c];
  }
#pragma unroll
  for (int mi = 0; mi < 2; ++mi)
#pragma unroll
    for (int reg = 0; reg < 4; ++reg) {
      int rloc = mi * 16 + er + reg;
      const float* xr = x + (size_t)(row0 + rloc) * D;
      float su = 0.f, s2 = 0.f;
#pragma unroll
      for (int nj = 0; nj < 4; ++nj) {
        float u = acc[mi][nj][reg] + bo_c[nj] + xr[wn + nj * 16 + ec];
        su += u; s2 += u * u;
      }
#pragma unroll
      for (int m = 1; m <= 8; m <<= 1) {
        su += __shfl_xor(su, m);
        s2 += __shfl_xor(s2, m);
      }
      if (ec == 0) { rsum[rloc][wv] = su; rsq[rloc][wv] = s2; }
    }
  __syncthreads();
#pragma unroll
  for (int mi = 0; mi < 2; ++mi)
#pragma unroll
    for (int reg = 0; reg < 4; ++reg) {
      int rloc = mi * 16 + er + reg;
      float s = rsum[rloc][0] + rsum[rloc][1] + rsum[rloc][2] + rsum[rloc][3];
      float q2 = rsq[rloc][0] + rsq[rloc][1] + rsq[rloc][2] + rsq[rloc][3];
      float mean = s * (1.0f / D);
      float var = q2 * (1.0f / D) - mean * mean;
      float rstd = rsqrtf(var + 1e-5f);
      const float* xr = x + (size_t)(row0 + rloc) * D;
      float* orow = out + (size_t)(row0 + rloc) * D;
#pragma unroll
      for (int nj = 0; nj < 4; ++nj) {
        float u = acc[mi][nj][reg] + bo_c[nj] + xr[wn + nj * 16 + ec];
        orow[wn + nj * 16 + ec] = (u - mean) * rstd * ga_c[nj] + be_c[nj];
      }
    }
}

// ---------------------------------------------------------------------------
// Workspace.  Common: XsN [0,8.39M) | sim [12.58M,79.69M) | norms@79.69M
//                     mask@79.99M | Wt@82.08M (ends 83,132,416)
// BIG (ws >= 125 MB; fill shows 256 MiB): qkv(bf16)@83.13M | aos@95.72M
// SMALL: qkv@12.58M, aos@37.75M (dead-sim region, written after topk)
// ---------------------------------------------------------------------------
extern "C" void kernel_launch(void* const* d_in, const int* in_sizes, int n_in,
                              void* d_out, int out_size, void* d_ws, size_t ws_size,
                              hipStream_t stream) {
  const float* x     = (const float*)d_in[0];
  const float* Wq    = (const float*)d_in[1];
  const float* Wk    = (const float*)d_in[2];
  const float* Wv    = (const float*)d_in[3];
  const float* Wo    = (const float*)d_in[4];
  const float* bo    = (const float*)d_in[5];
  const float* gamma = (const float*)d_in[6];
  const float* beta  = (const float*)d_in[7];
  float* out = (float*)d_out;

  char* ws = (char*)d_ws;
  bf16* XsN      = (bf16*)(ws);
  float* sim     = (float*)(ws + 12582912);
  float* norms   = (float*)(ws + 79691776);
  unsigned* mask = (unsigned*)(ws + 79986688);
  bf16* Wt       = (bf16*)(ws + 82083840);

  bool big = ws_size >= (size_t)125000000;
  bf16* qkv = (bf16*)(ws + (big ? 83132416 : 12582912));
  bf16* aos = (bf16*)(ws + (big ? 95715328 : 37748736));

  const int AMAP_SIM = PK6(0, 0, 1, 0, 0, 0);  // hh + hm + mh
  const int BMAP_SIM = PK6(0, 1, 0, 0, 0, 0);
  const int AMAP_2T  = PK3(0, 1, 0);           // (h+m)_A · h_B
  const int BMAP_2T  = PK3(0, 0, 1);

  prep_kernel<<<9344, 64, 0, stream>>>(x, Wq, Wk, Wv, Wo, XsN, Wt, norms,
                                       (uint4*)mask);

  if (big) {
    gemm_fused128x256_kernel<<<480, 256, 0, stream>>>(
        XsN, sim, AMAP_SIM, BMAP_SIM, Wt, qkv, AMAP_2T, BMAP_2T, norms);
    topk_adj_kernel<<<BATCH * N, 64, 0, stream>>>(sim, mask);
  } else {
    gemm_sim_kernel<<<544, 256, 0, stream>>>(XsN, sim, AMAP_SIM, BMAP_SIM);
    topk_adj_kernel<<<BATCH * N, 64, 0, stream>>>(sim, mask);
    gemm_qkv_kernel<<<dim3(6, 64), 256, 0, stream>>>(XsN, Wt, qkv,
                                                     AMAP_2T, BMAP_2T, norms);
  }

  attn_kernel<<<(BATCH * N) / 4, 256, 0, stream>>>(qkv, mask, aos);

  projln_kernel<<<256, 256, 0, stream>>>(aos, Wt + (size_t)768 * 512,
                                         x, bo, gamma, beta, out);
}